// Round 4
// baseline (222.818 us; speedup 1.0000x reference)
//
#include <hip/hip_runtime.h>
#include <hip/hip_bf16.h>
#include <stdint.h>

typedef unsigned short u16;
typedef unsigned int u32;
typedef __attribute__((ext_vector_type(8))) short short8;
typedef __attribute__((ext_vector_type(16))) float f32x16;

#define B_DIM 4096
#define D_DIM 1024
#define H_DIM 1024
#define K_DIM 2048   // D + H
#define N_DIM 4096   // 4H
#define LN_EPS 1e-5f

// ---------- helpers ----------
__device__ __forceinline__ u16 f2bf(float f) {
    union { float f; uint32_t u; } v; v.f = f;
    uint32_t u = v.u;
    uint32_t r = (u + 0x7FFFu + ((u >> 16) & 1u)) >> 16;  // RNE
    return (u16)r;
}
__device__ __forceinline__ float bf2f(u16 h) {
    union { uint32_t u; float f; } v; v.u = ((uint32_t)h) << 16;
    return v.f;
}
__device__ __forceinline__ void gld16(const u16* g, u16* l) {
    __builtin_amdgcn_global_load_lds(
        (const __attribute__((address_space(1))) void*)g,
        (__attribute__((address_space(3))) void*)l,
        16, 0, 0);
}
__device__ __forceinline__ float sigm(float x) { return 1.0f / (1.0f + __expf(-x)); }
__device__ __forceinline__ float tanh_fast(float x) { return 1.0f - 2.0f / (__expf(2.0f * x) + 1.0f); }

// ---------- kernel 1: fused prep ----------
// A-part unchanged. W-part rewritten: u32 k-pair packing + 16B-block swizzle
// (q ^ ((n>>2)&7)); writes are exactly 2-way bank-aliased (free), readout is
// 2x ds_read_b128 at 2-way (free) -- replaces 16 scalar ~8-way-conflicted
// ds_read_u16 per thread.
__global__ __launch_bounds__(256) void prep(const float* __restrict__ x,
                                            const float* __restrict__ h,
                                            const float* __restrict__ Wx,
                                            const float* __restrict__ Wh,
                                            u16* __restrict__ A,
                                            u16* __restrict__ Bt) {
    __shared__ u32 tileT[64 * 32];   // [n][kpair u32], block-swizzled
    const int t = threadIdx.x;
    if (blockIdx.x < 4096) {
        int id = blockIdx.x * 256 + t;
        int row = id >> 8;
        int col = (id & 255) * 8;
        const float* src = (col < D_DIM) ? (x + (size_t)row * D_DIM + col)
                                         : (h + (size_t)row * H_DIM + (col - D_DIM));
        float4 v0 = ((const float4*)src)[0];
        float4 v1 = ((const float4*)src)[1];
        union { u16 us[8]; uint4 u; } p;
        p.us[0] = f2bf(v0.x); p.us[1] = f2bf(v0.y); p.us[2] = f2bf(v0.z); p.us[3] = f2bf(v0.w);
        p.us[4] = f2bf(v1.x); p.us[5] = f2bf(v1.y); p.us[6] = f2bf(v1.z); p.us[7] = f2bf(v1.w);
        *(uint4*)(A + (size_t)id * 8) = p.u;
    } else {
        const int v = blockIdx.x - 4096;       // 0..2047 = 64 x 32
        const int n0 = (v & 63) * 64;
        const int k0 = (v >> 6) * 64;
        const int n4  = (t & 15) * 4;          // 0..60
        const int kp0 = t >> 4;                // 0..15
#pragma unroll
        for (int p = 0; p < 2; ++p) {
            const int kpair = kp0 + p * 16;    // 0..31
            const int k = k0 + kpair * 2;      // even; k,k+1 same matrix (D%64==0)
            const float* src = (k < D_DIM) ? (Wx + (size_t)k * N_DIM)
                                           : (Wh + (size_t)(k - D_DIM) * N_DIM);
            float4 w0 = *(const float4*)(src + n0 + n4);
            float4 w1 = *(const float4*)(src + N_DIM + n0 + n4);
            const float a0[4] = {w0.x, w0.y, w0.z, w0.w};
            const float a1[4] = {w1.x, w1.y, w1.z, w1.w};
            const int q = kpair >> 2, wd = kpair & 3;
#pragma unroll
            for (int j = 0; j < 4; ++j) {
                const int n = n4 + j;
                const u32 pk = (u32)f2bf(a0[j]) | ((u32)f2bf(a1[j]) << 16);
                tileT[n * 32 + ((q ^ ((n >> 2) & 7)) << 2) + wd] = pk;
            }
        }
        __syncthreads();
        const int n = t >> 2;
        const int qb = (t & 3) * 2;
        const int sw = (n >> 2) & 7;
        uint4 r0 = *(const uint4*)&tileT[n * 32 + ((qb ^ sw) << 2)];
        uint4 r1 = *(const uint4*)&tileT[n * 32 + (((qb + 1) ^ sw) << 2)];
        u16* dst = Bt + (size_t)(n0 + n) * K_DIM + k0 + (t & 3) * 16;
        *(uint4*)dst = r0;
        *(uint4*)(dst + 8) = r1;
    }
}

// ---------- kernel 2: GEMM (round-2 structure, best measured: 76.4 us) ----------
// 256x256 block, 8 waves (2M x 4N), per-wave 128x64 (acc[4][2] of 32x32x16).
// BK=64 as 2 K-halves. LDS [buf][ks][256 rows][32 u16], 16B-block XOR swizzle
// q ^= (row>>1)&3; linear gld16 dest + inverse-swizzled per-lane source.
// 8 phases / 2 K-tiles, ONE barrier per phase, MFMA consumes ds_reads directly
// (waves desync within phase; setprio arbitrates). vmcnt(8) at even phases.
__global__ __launch_bounds__(512, 2) void gemm_bf16(const u16* __restrict__ A,   // [4096][2048]
                                                    const u16* __restrict__ Bt,  // [4096][2048]
                                                    const float* __restrict__ bias,
                                                    u16* __restrict__ C) {       // [4096][4096]
    __shared__ u16 As[2][2][8192];   // [buf][ks][row*32 + swizzled col]
    __shared__ u16 Bs[2][2][8192];
    const int tid = threadIdx.x;
    const int wave = tid >> 6, lane = tid & 63;

    // bijective XCD swizzle (256 wgs % 8 == 0)
    const int bid = blockIdx.y * 16 + blockIdx.x;
    const int swz_bid = (bid & 7) * 32 + (bid >> 3);
    const int m0 = (swz_bid >> 4) * 256;
    const int n0 = (swz_bid & 15) * 256;

    const int wm = (wave & 1) * 128;     // 2 waves along M
    const int wn = (wave >> 1) * 64;     // 4 waves along N
    const int lr = lane & 31, half = lane >> 5;

    f32x16 acc[4][2] = {};

    // staging: dest row = pass*128 + wave*16 + (lane>>2), 16B-block = lane&3
    // src 16B-block = (lane&3) ^ ((lane>>3)&3)
    const int srow = wave * 16 + (lane >> 2);
    const int qsrc = (lane & 3) ^ ((lane >> 3) & 3);
    const u16* Asrc = A  + (size_t)(m0 + srow) * K_DIM + qsrc * 8;
    const u16* Bsrc = Bt + (size_t)(n0 + srow) * K_DIM + qsrc * 8;
    const int ldst = wave * 512;   // u16; + pass*4096

    auto stageA = [&](int buf, int tt, int ks) {
        const int ko = tt * 64 + ks * 32;
        gld16(Asrc + ko,                       &As[buf][ks][ldst]);
        gld16(Asrc + ko + (size_t)128 * K_DIM, &As[buf][ks][ldst + 4096]);
    };
    auto stageB = [&](int buf, int tt, int ks) {
        const int ko = tt * 64 + ks * 32;
        gld16(Bsrc + ko,                       &Bs[buf][ks][ldst]);
        gld16(Bsrc + ko + (size_t)128 * K_DIM, &Bs[buf][ks][ldst + 4096]);
    };

    const int sA = (lr >> 1) & 3;
    const int aoff = (wm + lr) * 32;
    const int boff = (wn + lr) * 32;

    short8 af[2][4], bf[2];

#define PHASE(BUF, KS, QJ, READ_A, STAGE_STMT, DO_VM)                                  \
    {                                                                                  \
        if (READ_A) {                                                                  \
            _Pragma("unroll")                                                          \
            for (int kk = 0; kk < 2; ++kk)                                             \
                _Pragma("unroll")                                                      \
                for (int i = 0; i < 4; ++i)                                            \
                    af[kk][i] = *(const short8*)(                                      \
                        &As[BUF][KS][aoff + i * 1024 + (((kk * 2 + half) ^ sA) << 3)]);\
        }                                                                              \
        _Pragma("unroll")                                                              \
        for (int kk = 0; kk < 2; ++kk)                                                 \
            bf[kk] = *(const short8*)(                                                 \
                &Bs[BUF][KS][boff + (QJ) * 1024 + (((kk * 2 + half) ^ sA) << 3)]);     \
        STAGE_STMT;                                                                    \
        __builtin_amdgcn_s_setprio(1);                                                 \
        _Pragma("unroll")                                                              \
        for (int kk = 0; kk < 2; ++kk)                                                 \
            _Pragma("unroll")                                                          \
            for (int i = 0; i < 4; ++i)                                                \
                acc[i][QJ] = __builtin_amdgcn_mfma_f32_32x32x16_bf16(                  \
                    af[kk][i], bf[kk], acc[i][QJ], 0, 0, 0);                           \
        __builtin_amdgcn_s_setprio(0);                                                 \
        if (DO_VM) asm volatile("s_waitcnt vmcnt(8)" ::: "memory");                    \
        __builtin_amdgcn_s_barrier();                                                  \
        asm volatile("" ::: "memory");                                                 \
    }

    // prologue: tile0 (both halves) + tile1 ks0; drain; barrier
    stageA(0, 0, 0); stageB(0, 0, 0);
    stageA(0, 0, 1); stageB(0, 0, 1);
    stageA(1, 1, 0); stageB(1, 1, 0);
    asm volatile("s_waitcnt vmcnt(0)" ::: "memory");
    __builtin_amdgcn_s_barrier();
    asm volatile("" ::: "memory");

    for (int it = 0; it < 16; ++it) {
        const int t = it * 2;
        // tile t (buf0)
        PHASE(0, 0, 0, true,  stageA(1, t + 1, 1), false);
        PHASE(0, 0, 1, false, stageB(1, t + 1, 1), true );
        PHASE(0, 1, 1, true,  stageA(0, t + 2, 0), false);
        PHASE(0, 1, 0, false, stageB(0, t + 2, 0), true );
        // tile t+1 (buf1)
        PHASE(1, 0, 0, true,  stageA(0, t + 2, 1), false);
        PHASE(1, 0, 1, false, stageB(0, t + 2, 1), true );
        PHASE(1, 1, 1, true,  stageA(1, t + 3, 0), false);
        PHASE(1, 1, 0, false, stageB(1, t + 3, 0), true );
    }
#undef PHASE

    // epilogue: 32x32 C/D layout col=lane&31, row=(reg&3)+8*(reg>>2)+4*(lane>>5)
#pragma unroll
    for (int i = 0; i < 4; ++i) {
#pragma unroll
        for (int j = 0; j < 2; ++j) {
            const int c = n0 + wn + 32 * j + lr;
            const float bb = bias[c];
#pragma unroll
            for (int reg = 0; reg < 16; ++reg) {
                const int row = m0 + wm + 32 * i + (reg & 3) + 8 * (reg >> 2) + 4 * half;
                C[(size_t)row * N_DIM + c] = f2bf(acc[i][j][reg] + bb);
            }
        }
    }
}

// ---------- kernel 3: LayerNorm + gates -- one WAVE per row ----------
// 64 lanes x 64 values (16 per gate), uint4 loads (1KB/instr/wave),
// pure shfl_xor butterfly reduction (no LDS, no __syncthreads).
__global__ __launch_bounds__(256) void ln_lstm(const u16* __restrict__ aT,     // [4096][4096] bf16
                                               const float* __restrict__ pc,   // prev_c
                                               const float* __restrict__ gamma,
                                               const float* __restrict__ beta,
                                               float* __restrict__ out) {      // [h | c]
    const int row = blockIdx.x * 4 + (threadIdx.x >> 6);
    const int lane = threadIdx.x & 63;
    const u16* ar = aT + (size_t)row * N_DIM;
    const int j0 = lane * 16;   // per-gate col start (16 cols per lane)

    union U4 { uint4 u; u16 us[8]; };
    U4 g8[4][2];
#pragma unroll
    for (int s = 0; s < 4; ++s) {
        g8[s][0].u = *(const uint4*)(ar + s * H_DIM + j0);
        g8[s][1].u = *(const uint4*)(ar + s * H_DIM + j0 + 8);
    }

    float sum = 0.f, ssq = 0.f;
#pragma unroll
    for (int s = 0; s < 4; ++s)
#pragma unroll
        for (int hh = 0; hh < 2; ++hh)
#pragma unroll
            for (int e = 0; e < 8; ++e) {
                float v = bf2f(g8[s][hh].us[e]);
                sum += v; ssq += v * v;
            }
#pragma unroll
    for (int m = 1; m < 64; m <<= 1) {
        sum += __shfl_xor(sum, m, 64);
        ssq += __shfl_xor(ssq, m, 64);
    }
    const float mu = sum * (1.0f / N_DIM);
    const float var = fmaxf(ssq * (1.0f / N_DIM) - mu * mu, 0.0f);
    const float rs = rsqrtf(var + LN_EPS);

    // process in 4-column slices to cap register pressure
#pragma unroll
    for (int r = 0; r < 4; ++r) {
        const int c0 = j0 + r * 4;
        float vv[4][4];
#pragma unroll
        for (int s = 0; s < 4; ++s) {
            float4 gm = *(const float4*)(gamma + s * H_DIM + c0);
            float4 bt = *(const float4*)(beta + s * H_DIM + c0);
            const int hh = r >> 1;
            const int e0 = (r & 1) * 4;
            vv[s][0] = (bf2f(g8[s][hh].us[e0 + 0]) - mu) * rs * gm.x + bt.x;
            vv[s][1] = (bf2f(g8[s][hh].us[e0 + 1]) - mu) * rs * gm.y + bt.y;
            vv[s][2] = (bf2f(g8[s][hh].us[e0 + 2]) - mu) * rs * gm.z + bt.z;
            vv[s][3] = (bf2f(g8[s][hh].us[e0 + 3]) - mu) * rs * gm.w + bt.w;
        }
        float4 c4 = *(const float4*)(pc + (size_t)row * H_DIM + c0);
        float cin[4] = {c4.x, c4.y, c4.z, c4.w};
        float nh[4], nc[4];
#pragma unroll
        for (int e = 0; e < 4; ++e) {
            float ig = sigm(vv[0][e]);
            float fg = sigm(vv[1][e]);
            float og = sigm(vv[2][e]);
            float gg = tanh_fast(vv[3][e]);
            nc[e] = fg * cin[e] + ig * gg;
            nh[e] = og * tanh_fast(nc[e]);
        }
        float4 h4 = {nh[0], nh[1], nh[2], nh[3]};
        float4 c4o = {nc[0], nc[1], nc[2], nc[3]};
        *(float4*)(out + (size_t)row * H_DIM + c0) = h4;
        *(float4*)(out + (size_t)B_DIM * H_DIM + (size_t)row * H_DIM + c0) = c4o;
    }
}

// ---------- launch ----------
extern "C" void kernel_launch(void* const* d_in, const int* in_sizes, int n_in,
                              void* d_out, int out_size, void* d_ws, size_t ws_size,
                              hipStream_t stream) {
    const float* x  = (const float*)d_in[0];
    const float* ph = (const float*)d_in[1];
    const float* pc = (const float*)d_in[2];
    const float* Wx = (const float*)d_in[3];
    const float* Wh = (const float*)d_in[4];
    const float* b  = (const float*)d_in[5];
    const float* gm = (const float*)d_in[6];
    const float* bt = (const float*)d_in[7];
    float* out = (float*)d_out;

    char* ws = (char*)d_ws;
    u16* Abf = (u16*)ws;                               // 16 MiB: [4096][2048] bf16
    u16* Btb = (u16*)(ws + (size_t)16 * 1024 * 1024);  // 16 MiB: [4096][2048] bf16
    u16* aT  = (u16*)(ws + (size_t)32 * 1024 * 1024);  // 32 MiB: [4096][4096] bf16

    prep<<<dim3(4096 + 2048), dim3(256), 0, stream>>>(x, ph, Wx, Wh, Abf, Btb);
    gemm_bf16<<<dim3(16, 16), dim3(512), 0, stream>>>(Abf, Btb, b, aT);
    ln_lstm<<<dim3(1024), dim3(256), 0, stream>>>(aT, pc, gm, bt, out);
}